// Round 7
// baseline (750.894 us; speedup 1.0000x reference)
//
#include <hip/hip_runtime.h>
#include <hip/hip_bf16.h>

typedef unsigned char u8;
typedef unsigned short u16;
typedef unsigned int u32;
typedef float f32x4 __attribute__((ext_vector_type(4)));
typedef short s16x8 __attribute__((ext_vector_type(8)));

#define MEM    2000
#define FEA    256
#define SLSTR  2056      // fp8 a row stride (bytes)
#define OSTR   265       // out-stage row stride (f32)
#define G1BASE 34816     // G1 ring slots 0..2 (slot 3 overlays sX at 0)
#define G2BASE 66560     // G2 ring 4x16384
#define POOLSZ 133120
#define OUTN   8388608   // 32*256*32*32

typedef const __attribute__((address_space(1))) u32* gp1;
typedef __attribute__((address_space(3))) u32* lp3;

__device__ __forceinline__ void gl_lds16(const void* g, void* l) {
    __builtin_amdgcn_global_load_lds((gp1)g, (lp3)l, 16, 0, 0);
}
__device__ __forceinline__ void pipe_bar() {
    __builtin_amdgcn_sched_barrier(0);
    __builtin_amdgcn_s_barrier();
    __builtin_amdgcn_sched_barrier(0);
}
__device__ __forceinline__ void lds_bar() {
    asm volatile("s_waitcnt lgkmcnt(0)" ::: "memory");
    pipe_bar();
}

__device__ __forceinline__ u16 f2b(float f) {
    u32 u = __builtin_bit_cast(u32, f);
    u = u + 0x7fffu + ((u >> 16) & 1u);
    return (u16)(u >> 16);
}
__device__ __forceinline__ u32 cvtpk(float a, float b) {
    u32 r;
    asm("v_cvt_pk_bf16_f32 %0, %1, %2" : "=v"(r) : "v"(a), "v"(b));
    return r;   // low16 = bf16(a), high16 = bf16(b)
}
__device__ __forceinline__ float unlo(u32 p) { return __builtin_bit_cast(float, p << 16); }
__device__ __forceinline__ float unhi(u32 p) { return __builtin_bit_cast(float, p & 0xffff0000u); }
// exact f32 -> e4m3fn (RNE) incl subnormals (prep only)
__device__ __forceinline__ u8 f2e4m3(float x) {
    float ax = fabsf(x);
    u32 s = (__builtin_bit_cast(u32, x) >> 24) & 0x80u;
    if (ax >= 448.f) return (u8)(s | 0x7e);
    if (ax < 0.015625f) {
        int q = (int)rintf(ax * 512.f);
        return (u8)(s | (u32)q);
    }
    int e = (int)(__builtin_bit_cast(u32, ax) >> 23) - 127;
    float scale = __builtin_bit_cast(float, (u32)((127 - e + 3) << 23));
    int q = (int)rintf(ax * scale);
    int E = e + 7;
    if (q == 16) { q = 8; E += 1; if (E > 15) return (u8)(s | 0x7e); }
    return (u8)(s | (u32)(E << 3) | (u32)(q & 7));
}
// fast f32 -> e4m3fn for v in {0} U [0.15, 64]
__device__ __forceinline__ u32 f2e4m3_fast(float v) {
    u32 u = __builtin_bit_cast(u32, v);
    u += 0x0007FFFFu + ((u >> 20) & 1u);
    int bb = (int)(u >> 20) - 0x3C0;
    return bb < 0 ? 0u : (u32)bb;
}

// ---------------- prep ----------------
__global__ __launch_bounds__(256) void prep_kernel(const float* __restrict__ W,
                                                   u16* __restrict__ Wbs,
                                                   u8* __restrict__ WTc,
                                                   float* __restrict__ sqv,
                                                   float* __restrict__ loss) {
    const int blk = blockIdx.x, t = threadIdx.x;
    const int m0 = blk * 8;
    {
        const int sl = t >> 5, cl = t & 31;
        const int slot = m0 + sl;
        const int ch0 = cl * 8;
        const float* wr = W + slot * 256 + ch0;
        f32x4 v0 = *(const f32x4*)wr;
        f32x4 v1 = *(const f32x4*)(wr + 4);
        float ss = v0[0]*v0[0] + v0[1]*v0[1] + v0[2]*v0[2] + v0[3]*v0[3]
                 + v1[0]*v1[0] + v1[1]*v1[1] + v1[2]*v1[2] + v1[3]*v1[3];
        ss += __shfl_xor(ss, 1); ss += __shfl_xor(ss, 2); ss += __shfl_xor(ss, 4);
        ss += __shfl_xor(ss, 8); ss += __shfl_xor(ss, 16);
        if (cl == 0) sqv[slot] = ss;
        s16x8 pk;
#pragma unroll
        for (int i = 0; i < 4; ++i) { pk[i] = (short)f2b(v0[i]); pk[4 + i] = (short)f2b(v1[i]); }
        *(s16x8*)&Wbs[slot * 256 + (ch0 ^ ((slot & 7) << 3))] = pk;
    }
    {
        const int ch = t;
        const int chunk = m0 >> 6, kl0 = m0 & 63;
        u32 lo = 0, hi = 0;
#pragma unroll
        for (int i = 0; i < 8; ++i) {
            u32 bb = f2e4m3(W[(m0 + i) * 256 + ch] * 16.f);
            if (i < 4) lo |= bb << (i * 8); else hi |= bb << ((i - 4) * 8);
        }
        u8* dst = WTc + chunk * 16384 + ch * 64 + (kl0 ^ ((ch & 7) << 3));
        *(u32*)dst = lo;
        *(u32*)(dst + 4) = hi;
    }
    if (blk == 0 && t == 0) {
        loss[0] = 0.0f;
        loss[1] = -2000.0f / (2000.0f * 1999.0f);
    }
}

// ---------------- main fused kernel: 64 rows/block, 512 blocks, forced 2 waves/EU ----------------
__global__ __attribute__((amdgpu_flat_work_group_size(512, 512), amdgpu_waves_per_eu(2, 2)))
void main_kernel(
        const float* __restrict__ inp, const float* __restrict__ posb,
        const u16* __restrict__ Wbs, const u8* __restrict__ WTc,
        const float* __restrict__ sqv, float* __restrict__ out,
        float* __restrict__ loss) {
    __shared__ __align__(16) u8 pool[POOLSZ];
    __shared__ float sPM[4][64];
    __shared__ float sPZ[4][64];
    __shared__ int   sPI[4][64];
    __shared__ float sPD[4][64];
    __shared__ float sSS[8][64];
    __shared__ float sMax[64];
    __shared__ float sThr[64];
    __shared__ float sInv[64];

    const int t = threadIdx.x;
    const int w = t >> 6, lane = t & 63;
    const int ar = lane & 15, ag = lane >> 4;
    const int blk = blockIdx.x, b = blk >> 4, hw0 = (blk & 15) << 6;
    const int rot = (blk >> 3) & 31;
    const int q = w & 3, rh = w >> 2;
    const u8* WbsB = (const u8*)Wbs;

    // ---- G1 prologue: chunks 0..2 -> slots 0..2 ----
#pragma unroll
    for (int c = 0; c < 3; ++c) {
        const int cc = (c + rot) & 31;
        const u8* src = WbsB + cc * 32768 + w * 4096 + lane * 16;
        u8* dst = pool + G1BASE + c * 32768 + w * 4096;
#pragma unroll
        for (int i = 0; i < 4; ++i) gl_lds16(src + i * 1024, dst + i * 1024);
    }

    // ---- stage xr (64 rows) as bf16 pairs + sum(x^2); plain 264-u16 stride ----
    {
        const float* ip = inp + (size_t)b * 262144 + hw0 + lane;
        const float* pp = posb + hw0 + lane;
        u16* sX = (u16*)pool;
        float ss = 0.f;
#pragma unroll
        for (int j = 0; j < 16; ++j) {
            const int ch = w * 32 + 2 * j;
            float v0 = ip[ch * 1024] + pp[ch * 1024];
            float v1 = ip[(ch + 1) * 1024] + pp[(ch + 1) * 1024];
            ss += v0 * v0 + v1 * v1;
            u32 pkx = (u32)f2b(v0) | ((u32)f2b(v1) << 16);
            *(u32*)(sX + lane * 264 + ch) = pkx;
        }
        sSS[w][lane] = ss;
    }
    lds_bar();

    // ---- xr B-fragments for this wave's 32 rows (2 row-tiles) ----
    s16x8 af[2][8];
    {
        const u16* sX = (const u16*)pool;
#pragma unroll
        for (int rl = 0; rl < 2; ++rl)
#pragma unroll
            for (int kk = 0; kk < 8; ++kk) {
                const int row = rh * 32 + rl * 16 + ar;
                af[rl][kk] = *(const s16x8*)(sX + row * 264 + kk * 32 + ag * 8);
            }
    }
    asm volatile("s_waitcnt lgkmcnt(0)" ::: "memory");
    __builtin_amdgcn_sched_barrier(0);

    // ---- GEMM1: stream Wbs; logits -> packed bf16 regs; online max/argmax/Z ----
    u32 pk[32][2][2];
    float bm[2] = {-3e38f, -3e38f};
    int   bi[2] = {0x7fffffff, 0x7fffffff};
    float zz[2] = {0.f, 0.f};
    {
        const int rowoff = (q * 16 + ar) * 512;
        const int swz = (ar & 7) << 4;
        const int c31 = (31 - rot) & 31;
#pragma unroll
        for (int c = 0; c < 32; ++c) {
            if (c <= 29)      asm volatile("s_waitcnt vmcnt(8)" ::: "memory");
            else if (c == 30) asm volatile("s_waitcnt vmcnt(4)" ::: "memory");
            else              asm volatile("s_waitcnt vmcnt(0)" ::: "memory");
            pipe_bar();
            if (c <= 28) {
                const int cn = (c + 3 + rot) & 31;
                const int sl = (c + 3) & 3;
                const u8* src = WbsB + cn * 32768 + w * 4096 + lane * 16;
                u8* dst = (sl == 3 ? pool : pool + G1BASE + sl * 32768) + w * 4096;
#pragma unroll
                for (int i = 0; i < 4; ++i) gl_lds16(src + i * 1024, dst + i * 1024);
            }
            const int cs = c & 3;
            const u8* base = (cs == 3 ? pool : pool + G1BASE + cs * 32768);
            f32x4 a0 = {0.f, 0.f, 0.f, 0.f}, a1 = {0.f, 0.f, 0.f, 0.f};
#pragma unroll
            for (int kk = 0; kk < 8; ++kk) {
                s16x8 wf = *(const s16x8*)(base + ((rowoff + kk * 64 + ag * 16) ^ swz));
                a0 = __builtin_amdgcn_mfma_f32_16x16x32_bf16(wf, af[0][kk], a0, 0, 0, 0);
                a1 = __builtin_amdgcn_mfma_f32_16x16x32_bf16(wf, af[1][kk], a1, 0, 0, 0);
            }
            if (c == c31 && q != 0) {
#pragma unroll
                for (int e = 0; e < 4; ++e) { a0[e] = -3e38f; a1[e] = -3e38f; }
            }
            const int sb = (((c + rot) & 31) << 6) + q * 16 + ag * 4;
#pragma unroll
            for (int rl = 0; rl < 2; ++rl) {
                f32x4 a = rl ? a1 : a0;
                float ob = bm[rl];
#pragma unroll
                for (int e = 0; e < 4; ++e) {
                    float v = a[e]; int id = sb + e;
                    bool g = (v > bm[rl]) || (v == bm[rl] && id < bi[rl]);
                    bm[rl] = g ? v : bm[rl];
                    bi[rl] = g ? id : bi[rl];
                }
                zz[rl] *= __expf(ob - bm[rl]);   // ==1 when max unchanged
                zz[rl] += __expf(a[0] - bm[rl]) + __expf(a[1] - bm[rl])
                        + __expf(a[2] - bm[rl]) + __expf(a[3] - bm[rl]);
                pk[c][rl][0] = cvtpk(a[0], a[1]);
                pk[c][rl][1] = cvtpk(a[2], a[3]);
            }
        }
    }

    // ---- combine (m,i,z) across ag lanes ----
#pragma unroll
    for (int rl = 0; rl < 2; ++rl) {
#pragma unroll
        for (int d = 16; d < 64; d <<= 1) {
            float om = __shfl_xor(bm[rl], d);
            int   oi = __shfl_xor(bi[rl], d);
            float oz = __shfl_xor(zz[rl], d);
            bool g = (om > bm[rl]) || (om == bm[rl] && oi < bi[rl]);
            float nm = g ? om : bm[rl];
            zz[rl] = zz[rl] * __expf(bm[rl] - nm) + oz * __expf(om - nm);
            bm[rl] = nm;
            bi[rl] = g ? oi : bi[rl];
        }
    }
    if (lane < 16) {
#pragma unroll
        for (int rl = 0; rl < 2; ++rl) {
            const int row = rh * 32 + rl * 16 + ar;
            sPM[q][row] = bm[rl];
            sPZ[q][row] = zz[rl];
            sPI[q][row] = bi[rl];
        }
    }

    // ---- G2 prologue (ring region: old G1 slots, now dead) ----
#pragma unroll
    for (int c = 0; c < 3; ++c) {
        const int cc = (c + rot) & 31;
        const u8* src = WTc + cc * 16384 + w * 2048 + lane * 16;
        u8* dst = pool + G2BASE + c * 16384 + w * 2048;
#pragma unroll
        for (int i = 0; i < 2; ++i) gl_lds16(src + i * 1024, dst + i * 1024);
    }
    lds_bar();

    // ---- combiner 1: row max/argmax/Z -> sMax/sThr; compact loss ----
    if (t < 64) {
        float M = sPM[0][t]; int I = sPI[0][t];
#pragma unroll
        for (int qq = 1; qq < 4; ++qq) {
            float m2 = sPM[qq][t]; int i2 = sPI[qq][t];
            bool g = (m2 > M) || (m2 == M && i2 < I);
            M = g ? m2 : M; I = g ? i2 : I;
        }
        float Z = 0.f;
#pragma unroll
        for (int qq = 0; qq < 4; ++qq) Z += sPZ[qq][t] * __expf(sPM[qq][t] - M);
        sMax[t] = M;
        sThr[t] = 0.0025f * Z;
        float ssq = 0.f;
#pragma unroll
        for (int ww = 0; ww < 8; ++ww) ssq += sSS[ww][t];
        float term = ssq - 2.f * M + sqv[I];
#pragma unroll
        for (int d = 1; d < 64; d <<= 1) term += __shfl_xor(term, d);
        if (t == 0) atomicAdd(loss, term * (1.0f / 8388608.0f));
    }
    lds_bar();

    // ---- exp-pass: a = exp(l-M); mask; den; fp8 pack; rh0 -> LDS, rh1 -> regs ----
    u32 d8[32][2];
    float den[2] = {0.f, 0.f};
    float Mr[2], Tr[2];
#pragma unroll
    for (int rl = 0; rl < 2; ++rl) {
        const int row = rh * 32 + rl * 16 + ar;
        Mr[rl] = sMax[row];
        Tr[rl] = sThr[row];
    }
#pragma unroll
    for (int c = 0; c < 32; ++c) {
        const int sb = (((c + rot) & 31) << 6) + q * 16 + ag * 4;
#pragma unroll
        for (int rl = 0; rl < 2; ++rl) {
            const u32 p0 = pk[c][rl][0], p1 = pk[c][rl][1];
            float a0 = __expf(unlo(p0) - Mr[rl]);
            float a1 = __expf(unhi(p0) - Mr[rl]);
            float a2 = __expf(unlo(p1) - Mr[rl]);
            float a3 = __expf(unhi(p1) - Mr[rl]);
            bool k0 = a0 > Tr[rl], k1 = a1 > Tr[rl], k2 = a2 > Tr[rl], k3 = a3 > Tr[rl];
            den[rl] += (k0 ? a0 : 0.f) + (k1 ? a1 : 0.f) + (k2 ? a2 : 0.f) + (k3 ? a3 : 0.f);
            u32 w32 = (k0 ? f2e4m3_fast(a0 * 64.f) : 0u)
                    | ((k1 ? f2e4m3_fast(a1 * 64.f) : 0u) << 8)
                    | ((k2 ? f2e4m3_fast(a2 * 64.f) : 0u) << 16)
                    | ((k3 ? f2e4m3_fast(a3 * 64.f) : 0u) << 24);
            if (rh == 0) *(u32*)(pool + (rl * 16 + ar) * SLSTR + sb) = w32;
            else d8[c][rl] = w32;
        }
    }
#pragma unroll
    for (int rl = 0; rl < 2; ++rl) {
        den[rl] += __shfl_xor(den[rl], 16);
        den[rl] += __shfl_xor(den[rl], 32);
    }
    if (lane < 16) {
#pragma unroll
        for (int rl = 0; rl < 2; ++rl) sPD[q][rh * 32 + rl * 16 + ar] = den[rl];
    }
    lds_bar();
    if (t < 64) {
        float dd = sPD[0][t] + sPD[1][t] + sPD[2][t] + sPD[3][t];
        sInv[t] = dd > 0.f ? 1.0f / (1024.0f * dd) : 0.0f;
    }
    lds_bar();

    // ---- GEMM2: two 32-row halves over streamed WTc ----
    const int ch0 = w * 32 + ar;
    const int ch1 = ch0 + 16;
    int bo[2][2];
#pragma unroll
    for (int kk = 0; kk < 2; ++kk) {
        bo[0][kk] = (ch0 * 64 + kk * 32 + ag * 8) ^ ((ch0 & 7) << 3);
        bo[1][kk] = (ch1 * 64 + kk * 32 + ag * 8) ^ ((ch1 & 7) << 3);
    }
    const u8* sLr0 = pool + ar * SLSTR + ag * 8;
    const u8* sLr1 = pool + (16 + ar) * SLSTR + ag * 8;
    f32x4 oA[2], oB[2], oC[2], oD[2];

#pragma unroll
    for (int h = 0; h < 2; ++h) {
        f32x4 o00 = {0.f,0.f,0.f,0.f}, o01 = {0.f,0.f,0.f,0.f};
        f32x4 o10 = {0.f,0.f,0.f,0.f}, o11 = {0.f,0.f,0.f,0.f};
#pragma unroll
        for (int c = 0; c < 32; ++c) {
            if (c <= 29)      asm volatile("s_waitcnt vmcnt(4)" ::: "memory");
            else if (c == 30) asm volatile("s_waitcnt vmcnt(2)" ::: "memory");
            else              asm volatile("s_waitcnt vmcnt(0)" ::: "memory");
            pipe_bar();
            if (c <= 28) {
                const int cn = (c + 3 + rot) & 31;
                const u8* src = WTc + cn * 16384 + w * 2048 + lane * 16;
                u8* dst = pool + G2BASE + (((c + 3) & 3) << 14) + w * 2048;
#pragma unroll
                for (int i = 0; i < 2; ++i) gl_lds16(src + i * 1024, dst + i * 1024);
            }
            const u8* base = pool + G2BASE + ((c & 3) << 14);
            const int cc64 = ((c + rot) & 31) << 6;
            long long A00 = *(const long long*)(sLr0 + cc64);
            long long A01 = *(const long long*)(sLr0 + cc64 + 32);
            long long A10 = *(const long long*)(sLr1 + cc64);
            long long A11 = *(const long long*)(sLr1 + cc64 + 32);
            long long B00 = *(const long long*)(base + bo[0][0]);
            long long B01 = *(const long long*)(base + bo[0][1]);
            long long B10 = *(const long long*)(base + bo[1][0]);
            long long B11 = *(const long long*)(base + bo[1][1]);
            o00 = __builtin_amdgcn_mfma_f32_16x16x32_fp8_fp8(A00, B00, o00, 0, 0, 0);
            o00 = __builtin_amdgcn_mfma_f32_16x16x32_fp8_fp8(A01, B01, o00, 0, 0, 0);
            o01 = __builtin_amdgcn_mfma_f32_16x16x32_fp8_fp8(A10, B00, o01, 0, 0, 0);
            o01 = __builtin_amdgcn_mfma_f32_16x16x32_fp8_fp8(A11, B01, o01, 0, 0, 0);
            o10 = __builtin_amdgcn_mfma_f32_16x16x32_fp8_fp8(A00, B10, o10, 0, 0, 0);
            o10 = __builtin_amdgcn_mfma_f32_16x16x32_fp8_fp8(A01, B11, o10, 0, 0, 0);
            o11 = __builtin_amdgcn_mfma_f32_16x16x32_fp8_fp8(A10, B10, o11, 0, 0, 0);
            o11 = __builtin_amdgcn_mfma_f32_16x16x32_fp8_fp8(A11, B11, o11, 0, 0, 0);
        }
        oA[h] = o00; oB[h] = o01; oC[h] = o10; oD[h] = o11;
        lds_bar();
        if (h == 0) {
            // dump rh=1 fp8 a into a-region (local rows 0..31 = global 32..63)
            if (rh == 1) {
#pragma unroll
                for (int c = 0; c < 32; ++c) {
                    const int sb = (((c + rot) & 31) << 6) + q * 16 + ag * 4;
#pragma unroll
                    for (int rl = 0; rl < 2; ++rl)
                        *(u32*)(pool + (rl * 16 + ar) * SLSTR + sb) = d8[c][rl];
                }
            }
            // h1 prologue
#pragma unroll
            for (int c = 0; c < 3; ++c) {
                const int cc = (c + rot) & 31;
                const u8* src = WTc + cc * 16384 + w * 2048 + lane * 16;
                u8* dst = pool + G2BASE + c * 16384 + w * 2048;
#pragma unroll
                for (int i = 0; i < 2; ++i) gl_lds16(src + i * 1024, dst + i * 1024);
            }
            lds_bar();
        }
    }

    // ---- out-stage both halves + coalesced store ----
    {
        float* sO = (float*)pool;
#pragma unroll
        for (int h = 0; h < 2; ++h) {
#pragma unroll
            for (int i = 0; i < 4; ++i) {
                const int r0 = h * 32 + ag * 4 + i;
                const int r1 = r0 + 16;
                sO[r0 * OSTR + ch0] = oA[h][i] * sInv[r0];
                sO[r1 * OSTR + ch0] = oB[h][i] * sInv[r1];
                sO[r0 * OSTR + ch1] = oC[h][i] * sInv[r0];
                sO[r1 * OSTR + ch1] = oD[h][i] * sInv[r1];
            }
        }
    }
    lds_bar();
    {
        const float* sO = (const float*)pool;
        float* op = out + (size_t)b * 262144 + hw0 + lane;
#pragma unroll
        for (int i = 0; i < 32; ++i) {
            const int ch = w * 32 + i;
            op[ch * 1024] = sO[lane * OSTR + ch];
        }
    }
}

// ---------------- distance loss (unchanged) ----------------
__global__ __launch_bounds__(256) void dist_kernel(const u16* __restrict__ Wbs,
                                                   const float* __restrict__ sqv,
                                                   float* __restrict__ dl) {
    __shared__ float red[4];
    int t = threadIdx.x, w = t >> 6, lane = t & 63;
    int ar = lane & 15, ag = lane >> 4;
    int i0 = blockIdx.x << 4;
    int si = i0 + ar;
    s16x8 af[8];
#pragma unroll
    for (int q = 0; q < 8; ++q)
        af[q] = *(const s16x8*)&Wbs[si * 256 + ((q * 32 + ag * 8) ^ ((si & 7) << 3))];
    float sqi[4];
#pragma unroll
    for (int e = 0; e < 4; ++e) sqi[e] = sqv[i0 + (ag << 2) + e];
    float sum = 0.f;
    for (int jt = w; jt < 125; jt += 4) {
        int j0 = jt << 4, sj0 = j0 + ar;
        f32x4 acc = {0.f, 0.f, 0.f, 0.f};
#pragma unroll
        for (int q = 0; q < 8; ++q) {
            s16x8 bf = *(const s16x8*)&Wbs[sj0 * 256 + ((q * 32 + ag * 8) ^ ((sj0 & 7) << 3))];
            acc = __builtin_amdgcn_mfma_f32_16x16x32_bf16(af[q], bf, acc, 0, 0, 0);
        }
        float sqj = sqv[sj0];
#pragma unroll
        for (int e = 0; e < 4; ++e) {
            float dist = 1.0f - (sqi[e] + sqj - 2.0f * acc[e]);
            sum += dist > 0.f ? dist : 0.f;
        }
    }
#pragma unroll
    for (int d = 1; d < 64; d <<= 1) sum += __shfl_xor(sum, d);
    if (lane == 0) red[w] = sum;
    __syncthreads();
    if (t == 0) {
        float s = red[0] + red[1] + red[2] + red[3];
        atomicAdd(dl, s * (1.0f / (2000.0f * 1999.0f)));
    }
}

extern "C" void kernel_launch(void* const* d_in, const int* in_sizes, int n_in,
                              void* d_out, int out_size, void* d_ws, size_t ws_size,
                              hipStream_t stream) {
    (void)in_sizes; (void)n_in; (void)out_size; (void)ws_size;
    const float* inp  = (const float*)d_in[0];
    const float* W    = (const float*)d_in[2];
    const float* posb = (const float*)d_in[3];
    float* out = (float*)d_out;

    u16* Wbs = (u16*)d_ws;                                   // 2048*256*2 = 1,048,576 B
    u8*  WTc = (u8*)d_ws + 1048576;                          // 32*16384   =   524,288 B
    float* sqv = (float*)((u8*)d_ws + 1048576 + 524288);     // 2000*4     =     8,000 B

    hipLaunchKernelGGL(prep_kernel, dim3(250), dim3(256), 0, stream, W, Wbs, WTc, sqv, out + OUTN);
    hipLaunchKernelGGL(main_kernel, dim3(512), dim3(512), 0, stream, inp, posb, Wbs, WTc, sqv, out, out + OUTN);
    hipLaunchKernelGGL(dist_kernel, dim3(125), dim3(256), 0, stream, Wbs, sqv, out + OUTN + 1);
}

// Round 8
// 180.792 us; speedup vs baseline: 4.1534x; 4.1534x over previous
//
#include <hip/hip_runtime.h>
#include <hip/hip_bf16.h>

typedef unsigned char u8;
typedef unsigned short u16;
typedef unsigned int u32;
typedef long long s64;
typedef float f32x4 __attribute__((ext_vector_type(4)));

#define MEM    2000
#define FEA    256
#define SLSTR  2056      // fp8 a row stride (bytes)
#define OSTR   265       // out-stage row stride (f32)
#define XRS    264       // xr fp8 row stride (bytes)
#define RING   65792     // ring base = 32*SLSTR; 4 x 16384
#define POOLSZ 131328
#define OUTN   8388608   // 32*256*32*32

typedef const __attribute__((address_space(1))) u32* gp1;
typedef __attribute__((address_space(3))) u32* lp3;

__device__ __forceinline__ void gl_lds16(const void* g, void* l) {
    __builtin_amdgcn_global_load_lds((gp1)g, (lp3)l, 16, 0, 0);
}
__device__ __forceinline__ void pipe_bar() {
    __builtin_amdgcn_sched_barrier(0);
    __builtin_amdgcn_s_barrier();
    __builtin_amdgcn_sched_barrier(0);
}
__device__ __forceinline__ void lds_bar() {
    asm volatile("s_waitcnt lgkmcnt(0)" ::: "memory");
    pipe_bar();
}

// exact f32 -> e4m3fn (RNE) incl subnormals
__device__ __forceinline__ u32 f2e4m3(float x) {
    float ax = fabsf(x);
    u32 s = (__builtin_bit_cast(u32, x) >> 24) & 0x80u;
    if (ax >= 448.f) return s | 0x7e;
    if (ax < 0.015625f) {
        int q = (int)rintf(ax * 512.f);
        return s | (u32)q;
    }
    int e = (int)(__builtin_bit_cast(u32, ax) >> 23) - 127;
    float scale = __builtin_bit_cast(float, (u32)((127 - e + 3) << 23));
    int q = (int)rintf(ax * scale);
    int E = e + 7;
    if (q == 16) { q = 8; E += 1; if (E > 15) return s | 0x7e; }
    return s | (u32)(E << 3) | (u32)(q & 7);
}
// fast f32 -> e4m3fn for v in {0} U [0.15, 64]
__device__ __forceinline__ u32 f2e4m3_fast(float v) {
    u32 u = __builtin_bit_cast(u32, v);
    u += 0x0007FFFFu + ((u >> 20) & 1u);
    int bb = (int)(u >> 20) - 0x3C0;
    return bb < 0 ? 0u : (u32)bb;
}

// ---------------- prep: WTc (fp8 W^T x16), Wc (fp8 W x16, fragment-ordered), sqv ----------
// Wc layout per 64-slot chunk c: byte[ c*16384 + ((kk*4+ag)*64 + s)*8 + j ] = fp8(W[c*64+s][kk*32+ag*8+j]*16)
__global__ __launch_bounds__(256) void prep_kernel(const float* __restrict__ W,
                                                   u8* __restrict__ WTc,
                                                   u8* __restrict__ Wc,
                                                   float* __restrict__ sqv,
                                                   float* __restrict__ loss) {
    const int blk = blockIdx.x, t = threadIdx.x;
    const int m0 = blk * 8;
    // --- Wc + sqv: thread (sl = t>>5, cl = t&31), 8 contiguous channels ---
    {
        const int sl = t >> 5, cl = t & 31;
        const int slot = m0 + sl;
        const int ch0 = cl * 8;
        const float* wr = W + slot * 256 + ch0;
        f32x4 v0 = *(const f32x4*)wr;
        f32x4 v1 = *(const f32x4*)(wr + 4);
        float ss = v0[0]*v0[0] + v0[1]*v0[1] + v0[2]*v0[2] + v0[3]*v0[3]
                 + v1[0]*v1[0] + v1[1]*v1[1] + v1[2]*v1[2] + v1[3]*v1[3];
        ss += __shfl_xor(ss, 1); ss += __shfl_xor(ss, 2); ss += __shfl_xor(ss, 4);
        ss += __shfl_xor(ss, 8); ss += __shfl_xor(ss, 16);
        if (cl == 0) sqv[slot] = ss;
        const int c = slot >> 6, s = slot & 63;
        const int kk = cl >> 2, agp = cl & 3;
        u32 lo = 0, hi = 0;
#pragma unroll
        for (int i = 0; i < 4; ++i) {
            lo |= f2e4m3(v0[i] * 16.f) << (i * 8);
            hi |= f2e4m3(v1[i] * 16.f) << (i * 8);
        }
        u8* dst = Wc + c * 16384 + (size_t)((kk * 4 + agp) * 64 + s) * 8;
        *(u32*)dst = lo;
        *(u32*)(dst + 4) = hi;
    }
    // --- WTc: thread = channel; 8 slots of this block; fp8(w*16) packed 8B, kl-XOR swizzle ---
    {
        const int ch = t;
        const int chunk = m0 >> 6, kl0 = m0 & 63;
        u32 lo = 0, hi = 0;
#pragma unroll
        for (int i = 0; i < 8; ++i) {
            u32 bb = f2e4m3(W[(m0 + i) * 256 + ch] * 16.f);
            if (i < 4) lo |= bb << (i * 8); else hi |= bb << ((i - 4) * 8);
        }
        u8* dst = WTc + chunk * 16384 + ch * 64 + (kl0 ^ ((ch & 7) << 3));
        *(u32*)dst = lo;
        *(u32*)(dst + 4) = hi;
    }
    if (blk == 0 && t == 0) {
        loss[0] = 0.0f;
        loss[1] = -2000.0f / (2000.0f * 1999.0f);
    }
}

// ---------------- main fused kernel: 32 rows/block, 1024 blocks ----------------
__global__ __launch_bounds__(512, 1) void main_kernel(
        const float* __restrict__ inp, const float* __restrict__ posb,
        const u8* __restrict__ Wc, const u8* __restrict__ WTc,
        const float* __restrict__ sqv, float* __restrict__ out,
        float* __restrict__ loss) {
    __shared__ __align__(16) u8 pool[POOLSZ];
    __shared__ float sPM[4][32];
    __shared__ int   sPI[4][32];
    __shared__ float sPZ[4][32];
    __shared__ float sPD[4][32];
    __shared__ float sSS[8][32];
    __shared__ float sMax[32];
    __shared__ float sThr[32];
    __shared__ float sInv[32];

    const int t = threadIdx.x;
    const int w = t >> 6, lane = t & 63;
    const int ar = lane & 15, ag = lane >> 4;
    const int blk = blockIdx.x, b = blk >> 5, hw0 = (blk & 31) << 5;
    const int prot = ((blk >> 3) & 15) * 2;      // even chunk-rotation (pairs stay aligned)
    const int q = w & 3, rt = w >> 2;
    const int row_a = rt * 16 + ar;

    // ---- G1 prologue: logical chunks 0,1 -> ring slots 0,1 ----
#pragma unroll
    for (int u = 0; u < 2; ++u) {
        const int pc = (u + prot) & 31;
        const u8* src = Wc + pc * 16384 + w * 2048 + lane * 16;
        u8* dst = pool + RING + u * 16384 + w * 2048;
        gl_lds16(src, dst);
        gl_lds16(src + 1024, dst + 1024);
    }

    // ---- stage xr as fp8 (x*4), row stride XRS; per-row sum(x^2) ----
    {
        const int hw = t & 31, cg = t >> 5;      // cg 0..15, 16 channels each
        const float* ip = inp + (size_t)b * 262144 + hw0 + hw;
        const float* pp = posb + hw0 + hw;
        float ss = 0.f;
        u8* xrow = pool + hw * XRS + cg * 16;
#pragma unroll
        for (int j = 0; j < 8; ++j) {
            const int ch = cg * 16 + 2 * j;
            float v0 = ip[ch * 1024] + pp[ch * 1024];
            float v1 = ip[(ch + 1) * 1024] + pp[(ch + 1) * 1024];
            ss += v0 * v0 + v1 * v1;
            u16 pk2 = (u16)(f2e4m3(v0 * 4.f) | (f2e4m3(v1 * 4.f) << 8));
            *(u16*)(xrow + 2 * j) = pk2;
        }
        ss += __shfl_xor(ss, 32);
        if (lane < 32) sSS[w][lane] = ss;
    }
    lds_bar();

    // ---- xr B-fragments: row_a, full K=256 (8 x 8B) ----
    s64 xB[8];
#pragma unroll
    for (int kk = 0; kk < 8; ++kk)
        xB[kk] = *(const s64*)(pool + row_a * XRS + kk * 32 + ag * 8);
    asm volatile("s_waitcnt lgkmcnt(0)" ::: "memory");
    __builtin_amdgcn_sched_barrier(0);

    // ---- GEMM1 (fp8): acc[c][e] = 64*logit[row_a][slot = pc*64 + q*16 + ag*4 + e] ----
    f32x4 acc[32];
    const int c31 = (31 - prot) & 31;            // logical index of physical chunk 31
#pragma unroll
    for (int i = 0; i < 16; ++i) {
        asm volatile("s_waitcnt vmcnt(0)" ::: "memory");
        pipe_bar();
        if (i < 15) {
#pragma unroll
            for (int u = 0; u < 2; ++u) {
                const int cl = 2 * i + 2 + u;
                const int pc = (cl + prot) & 31;
                const u8* src = Wc + pc * 16384 + w * 2048 + lane * 16;
                u8* dst = pool + RING + (cl & 3) * 16384 + w * 2048;
                gl_lds16(src, dst);
                gl_lds16(src + 1024, dst + 1024);
            }
        }
#pragma unroll
        for (int u = 0; u < 2; ++u) {
            const int cl = 2 * i + u;
            const u8* base = pool + RING + (cl & 3) * 16384;
            f32x4 a = {0.f, 0.f, 0.f, 0.f};
#pragma unroll
            for (int kk = 0; kk < 8; ++kk) {
                s64 wA = *(const s64*)(base + ((kk * 4 + ag) * 64 + q * 16 + ar) * 8);
                a = __builtin_amdgcn_mfma_f32_16x16x32_fp8_fp8(wA, xB[kk], a, 0, 0, 0);
            }
            if (cl == c31 && q != 0) { a[0] = -3e38f; a[1] = -3e38f; a[2] = -3e38f; a[3] = -3e38f; }
            acc[cl] = a;
        }
    }

    // ---- per-thread max + argmax (one row per thread) ----
    {
        float bm = -3e38f; int bi = 0x7fffffff;
#pragma unroll
        for (int c = 0; c < 32; ++c) {
            const int cb = (((c + prot) & 31) << 6) + q * 16 + ag * 4;
#pragma unroll
            for (int e = 0; e < 4; ++e) {
                float f = acc[c][e];
                int id = cb + e;
                if (f > bm || (f == bm && id < bi)) { bm = f; bi = id; }
            }
        }
#pragma unroll
        for (int d = 16; d < 64; d <<= 1) {
            float om = __shfl_xor(bm, d);
            int   oi = __shfl_xor(bi, d);
            if (om > bm || (om == bm && oi < bi)) { bm = om; bi = oi; }
        }
        if (lane < 16) { sPM[q][rt * 16 + lane] = bm; sPI[q][rt * 16 + lane] = bi; }
    }

    // ---- G2 prologue: logical chunks 0,1 -> ring slots 0,1 (G1 done with them) ----
#pragma unroll
    for (int u = 0; u < 2; ++u) {
        const int pc = (u + prot) & 31;
        const u8* src = WTc + pc * 16384 + w * 2048 + lane * 16;
        u8* dst = pool + RING + u * 16384 + w * 2048;
        gl_lds16(src, dst);
        gl_lds16(src + 1024, dst + 1024);
    }
    lds_bar();

    // ---- combine max/argmax + compact loss (logit = acc/64) ----
    if (t < 32) {
        float mx = sPM[0][t]; int bid = sPI[0][t];
#pragma unroll
        for (int qq = 1; qq < 4; ++qq) {
            float m2 = sPM[qq][t]; int i2 = sPI[qq][t];
            if (m2 > mx || (m2 == mx && i2 < bid)) { mx = m2; bid = i2; }
        }
        sMax[t] = mx;
        float ssq = 0.f;
#pragma unroll
        for (int ww = 0; ww < 8; ++ww) ssq += sSS[ww][t];
        float term = ssq - 2.f * (mx * 0.015625f) + sqv[bid];
#pragma unroll
        for (int d = 1; d < 32; d <<= 1) term += __shfl_xor(term, d);
        if (t == 0) atomicAdd(loss, term * (1.0f / 8388608.0f));
    }
    lds_bar();

    // ---- exp (in-place, scale 1/64) + Z ----
    {
        const float mxv = sMax[row_a];
        float z = 0.f;
#pragma unroll
        for (int c = 0; c < 32; ++c)
#pragma unroll
            for (int e = 0; e < 4; ++e) {
                float a_ = __expf((acc[c][e] - mxv) * 0.015625f);
                acc[c][e] = a_;
                z += a_;
            }
        z += __shfl_xor(z, 16); z += __shfl_xor(z, 32);
        if (lane < 16) sPZ[q][rt * 16 + lane] = z;
    }
    lds_bar();
    if (t < 32) sThr[t] = 0.0025f * (sPZ[0][t] + sPZ[1][t] + sPZ[2][t] + sPZ[3][t]);
    lds_bar();

    // ---- shrink mask + denom + packed fp8 a-write (u32 per chunk) ----
    {
        const float thrv = sThr[row_a];
        const int rowbase = row_a * SLSTR + q * 16 + ag * 4;
        float den = 0.f;
#pragma unroll
        for (int c = 0; c < 32; ++c) {
            const int off = rowbase + (((c + prot) & 31) << 6);
            u32 pk = 0;
#pragma unroll
            for (int e = 0; e < 4; ++e) {
                float a_ = acc[c][e];
                if (a_ > thrv) { den += a_; pk |= f2e4m3_fast(a_ * 64.f) << (e * 8); }
            }
            *(u32*)(pool + off) = pk;
        }
        den += __shfl_xor(den, 16); den += __shfl_xor(den, 32);
        if (lane < 16) sPD[q][rt * 16 + lane] = den;
    }
    lds_bar();
    if (t < 32) {
        float dd = sPD[0][t] + sPD[1][t] + sPD[2][t] + sPD[3][t];
        sInv[t] = dd > 0.f ? 1.0f / (1024.0f * dd) : 0.0f;
    }
    lds_bar();

    // ---- GEMM2: out = a_fp8 @ WT_fp8, 2 chunks/barrier ----
    const int ch0 = (w * 2) * 16 + ar;
    const int ch1 = ch0 + 16;
    int bo[2][2];
#pragma unroll
    for (int kk = 0; kk < 2; ++kk) {
        bo[0][kk] = (ch0 * 64 + kk * 32 + ag * 8) ^ ((ch0 & 7) << 3);
        bo[1][kk] = (ch1 * 64 + kk * 32 + ag * 8) ^ ((ch1 & 7) << 3);
    }
    const u8* sLr0 = pool + ar * SLSTR + ag * 8;
    const u8* sLr1 = pool + (16 + ar) * SLSTR + ag * 8;
    f32x4 o00 = {0.f,0.f,0.f,0.f}, o01 = {0.f,0.f,0.f,0.f};
    f32x4 o10 = {0.f,0.f,0.f,0.f}, o11 = {0.f,0.f,0.f,0.f};
#pragma unroll
    for (int i = 0; i < 16; ++i) {
        asm volatile("s_waitcnt vmcnt(0)" ::: "memory");
        pipe_bar();
        if (i < 15) {
#pragma unroll
            for (int u = 0; u < 2; ++u) {
                const int cl = 2 * i + 2 + u;
                const int pc = (cl + prot) & 31;
                const u8* src = WTc + pc * 16384 + w * 2048 + lane * 16;
                u8* dst = pool + RING + (cl & 3) * 16384 + w * 2048;
                gl_lds16(src, dst);
                gl_lds16(src + 1024, dst + 1024);
            }
        }
#pragma unroll
        for (int u = 0; u < 2; ++u) {
            const int cl = 2 * i + u;
            const u8* base = pool + RING + (cl & 3) * 16384;
            const int cc64 = ((cl + prot) & 31) << 6;
            s64 A00 = *(const s64*)(sLr0 + cc64);
            s64 A01 = *(const s64*)(sLr0 + cc64 + 32);
            s64 A10 = *(const s64*)(sLr1 + cc64);
            s64 A11 = *(const s64*)(sLr1 + cc64 + 32);
            s64 B00 = *(const s64*)(base + bo[0][0]);
            s64 B01 = *(const s64*)(base + bo[0][1]);
            s64 B10 = *(const s64*)(base + bo[1][0]);
            s64 B11 = *(const s64*)(base + bo[1][1]);
            o00 = __builtin_amdgcn_mfma_f32_16x16x32_fp8_fp8(A00, B00, o00, 0, 0, 0);
            o00 = __builtin_amdgcn_mfma_f32_16x16x32_fp8_fp8(A01, B01, o00, 0, 0, 0);
            o01 = __builtin_amdgcn_mfma_f32_16x16x32_fp8_fp8(A10, B00, o01, 0, 0, 0);
            o01 = __builtin_amdgcn_mfma_f32_16x16x32_fp8_fp8(A11, B01, o01, 0, 0, 0);
            o10 = __builtin_amdgcn_mfma_f32_16x16x32_fp8_fp8(A00, B10, o10, 0, 0, 0);
            o10 = __builtin_amdgcn_mfma_f32_16x16x32_fp8_fp8(A01, B11, o10, 0, 0, 0);
            o11 = __builtin_amdgcn_mfma_f32_16x16x32_fp8_fp8(A10, B10, o11, 0, 0, 0);
            o11 = __builtin_amdgcn_mfma_f32_16x16x32_fp8_fp8(A11, B11, o11, 0, 0, 0);
        }
    }
    lds_bar();   // all a/ring reads done; reuse pool as f32 out-stage

    {
        float* sO = (float*)pool;
#pragma unroll
        for (int i = 0; i < 4; ++i) {
            int r0 = ag * 4 + i, r1 = 16 + ag * 4 + i;
            sO[r0 * OSTR + ch0] = o00[i] * sInv[r0];
            sO[r1 * OSTR + ch0] = o01[i] * sInv[r1];
            sO[r0 * OSTR + ch1] = o10[i] * sInv[r0];
            sO[r1 * OSTR + ch1] = o11[i] * sInv[r1];
        }
    }
    lds_bar();
    {
        const float* sO = (const float*)pool;
        const int hw = t & 31, cq = t >> 5;
        float* op = out + (size_t)b * 262144 + hw0 + hw;
#pragma unroll
        for (int i = 0; i < 16; ++i) {
            int ch = cq + (i << 4);
            op[ch * 1024] = sO[hw * OSTR + ch];
        }
    }
}

// ---------------- distance loss from fp8 Wc (W*16): acc/256 = <w_i,w_j> ----------------
__global__ __launch_bounds__(256) void dist_kernel(const u8* __restrict__ Wc,
                                                   const float* __restrict__ sqv,
                                                   float* __restrict__ dl) {
    __shared__ float red[4];
    int t = threadIdx.x, w = t >> 6, lane = t & 63;
    int ar = lane & 15, ag = lane >> 4;
    const int i0 = blockIdx.x << 4;
    const int ci = i0 >> 6, si0 = i0 & 63;
    s64 af8[8];
#pragma unroll
    for (int kk = 0; kk < 8; ++kk)
        af8[kk] = *(const s64*)(Wc + ci * 16384 + (size_t)((kk * 4 + ag) * 64 + si0 + ar) * 8);
    float sqi[4];
#pragma unroll
    for (int e = 0; e < 4; ++e) sqi[e] = sqv[i0 + ag * 4 + e];
    float sum = 0.f;
    for (int jt = w; jt < 125; jt += 4) {
        const int j0 = jt << 4;
        const int cj = j0 >> 6, sj0 = j0 & 63;
        f32x4 acc = {0.f, 0.f, 0.f, 0.f};
#pragma unroll
        for (int kk = 0; kk < 8; ++kk) {
            s64 bf = *(const s64*)(Wc + cj * 16384 + (size_t)((kk * 4 + ag) * 64 + sj0 + ar) * 8);
            acc = __builtin_amdgcn_mfma_f32_16x16x32_fp8_fp8(af8[kk], bf, acc, 0, 0, 0);
        }
        float sqj = sqv[j0 + ar];
#pragma unroll
        for (int e = 0; e < 4; ++e) {
            float dist = 1.0f - (sqi[e] + sqj - acc[e] * 0.0078125f);
            sum += dist > 0.f ? dist : 0.f;
        }
    }
#pragma unroll
    for (int d = 1; d < 64; d <<= 1) sum += __shfl_xor(sum, d);
    if (lane == 0) red[w] = sum;
    __syncthreads();
    if (t == 0) {
        float s = red[0] + red[1] + red[2] + red[3];
        atomicAdd(dl, s * (1.0f / (2000.0f * 1999.0f)));
    }
}

extern "C" void kernel_launch(void* const* d_in, const int* in_sizes, int n_in,
                              void* d_out, int out_size, void* d_ws, size_t ws_size,
                              hipStream_t stream) {
    (void)in_sizes; (void)n_in; (void)out_size; (void)ws_size;
    const float* inp  = (const float*)d_in[0];
    const float* W    = (const float*)d_in[2];
    const float* posb = (const float*)d_in[3];
    float* out = (float*)d_out;

    u8* WTc = (u8*)d_ws;                                     // 32*16384 = 524,288 B
    u8* Wc  = (u8*)d_ws + 524288;                            // 32*16384 = 524,288 B
    float* sqv = (float*)((u8*)d_ws + 1048576);              // 2000*4   =   8,000 B

    hipLaunchKernelGGL(prep_kernel, dim3(250), dim3(256), 0, stream, W, WTc, Wc, sqv, out + OUTN);
    hipLaunchKernelGGL(main_kernel, dim3(1024), dim3(512), 0, stream, inp, posb, Wc, WTc, sqv, out, out + OUTN);
    hipLaunchKernelGGL(dist_kernel, dim3(125), dim3(256), 0, stream, Wc, sqv, out + OUTN + 1);
}

// Round 9
// 174.263 us; speedup vs baseline: 4.3090x; 1.0375x over previous
//
#include <hip/hip_runtime.h>
#include <hip/hip_bf16.h>

typedef unsigned char u8;
typedef unsigned short u16;
typedef unsigned int u32;
typedef long long s64;
typedef float f32x4 __attribute__((ext_vector_type(4)));
typedef long long s64x2 __attribute__((ext_vector_type(2)));

#define MEM    2000
#define FEA    256
#define SLSTR  2064      // fp8 a row stride (bytes), 16B-aligned
#define OSTR   265       // out-stage row stride (f32)
#define XRS    264       // xr fp8 row stride (bytes)
#define XRBASE 98304     // xr region (after 6-slot G1 ring)
#define RING2  66048     // G2 ring base = 32*SLSTR; 4 x 16384
#define POOLSZ 131584    // RING2 + 4*16384
#define OUTN   8388608   // 32*256*32*32

typedef const __attribute__((address_space(1))) u32* gp1;
typedef __attribute__((address_space(3))) u32* lp3;

__device__ __forceinline__ void gl_lds16(const void* g, void* l) {
    __builtin_amdgcn_global_load_lds((gp1)g, (lp3)l, 16, 0, 0);
}
__device__ __forceinline__ void pipe_bar() {
    __builtin_amdgcn_sched_barrier(0);
    __builtin_amdgcn_s_barrier();
    __builtin_amdgcn_sched_barrier(0);
}
__device__ __forceinline__ void lds_bar() {
    asm volatile("s_waitcnt lgkmcnt(0)" ::: "memory");
    pipe_bar();
}

// exact f32 -> e4m3fn (RNE) incl subnormals
__device__ __forceinline__ u32 f2e4m3(float x) {
    float ax = fabsf(x);
    u32 s = (__builtin_bit_cast(u32, x) >> 24) & 0x80u;
    if (ax >= 448.f) return s | 0x7e;
    if (ax < 0.015625f) {
        int q = (int)rintf(ax * 512.f);
        return s | (u32)q;
    }
    int e = (int)(__builtin_bit_cast(u32, ax) >> 23) - 127;
    float scale = __builtin_bit_cast(float, (u32)((127 - e + 3) << 23));
    int q = (int)rintf(ax * scale);
    int E = e + 7;
    if (q == 16) { q = 8; E += 1; if (E > 15) return s | 0x7e; }
    return s | (u32)(E << 3) | (u32)(q & 7);
}
// fast f32 -> e4m3fn for v in {0} U [0.15, 64]
__device__ __forceinline__ u32 f2e4m3_fast(float v) {
    u32 u = __builtin_bit_cast(u32, v);
    u += 0x0007FFFFu + ((u >> 20) & 1u);
    int bb = (int)(u >> 20) - 0x3C0;
    return bb < 0 ? 0u : (u32)bb;
}

// ---------------- prep: WTc (fp8 W^T x16, swizzled), Wc (fp8 W x16, paired-k frag order), sqv
// Wc per 64-slot chunk c: byte[c*16384 + ((kp*4+ag)*64 + s)*16 + klo*8 + j]
//   = fp8( W[c*64+s][(2*kp+klo)*32 + ag*8 + j] * 16 )
__global__ __launch_bounds__(256) void prep_kernel(const float* __restrict__ W,
                                                   u8* __restrict__ WTc,
                                                   u8* __restrict__ Wc,
                                                   float* __restrict__ sqv,
                                                   float* __restrict__ loss) {
    const int blk = blockIdx.x, t = threadIdx.x;
    const int m0 = blk * 8;
    // --- Wc + sqv: thread (sl = t>>5, cl = t&31), 8 contiguous channels ---
    {
        const int sl = t >> 5, cl = t & 31;
        const int slot = m0 + sl;
        const int ch0 = cl * 8;
        const float* wr = W + slot * 256 + ch0;
        f32x4 v0 = *(const f32x4*)wr;
        f32x4 v1 = *(const f32x4*)(wr + 4);
        float ss = v0[0]*v0[0] + v0[1]*v0[1] + v0[2]*v0[2] + v0[3]*v0[3]
                 + v1[0]*v1[0] + v1[1]*v1[1] + v1[2]*v1[2] + v1[3]*v1[3];
        ss += __shfl_xor(ss, 1); ss += __shfl_xor(ss, 2); ss += __shfl_xor(ss, 4);
        ss += __shfl_xor(ss, 8); ss += __shfl_xor(ss, 16);
        if (cl == 0) sqv[slot] = ss;
        const int c = slot >> 6, s = slot & 63;
        const int kk = cl >> 2, agp = cl & 3;
        const int kp = kk >> 1, klo = kk & 1;
        u32 lo = 0, hi = 0;
#pragma unroll
        for (int i = 0; i < 4; ++i) {
            lo |= f2e4m3(v0[i] * 16.f) << (i * 8);
            hi |= f2e4m3(v1[i] * 16.f) << (i * 8);
        }
        u8* dst = Wc + c * 16384 + (size_t)((kp * 4 + agp) * 64 + s) * 16 + klo * 8;
        *(u32*)dst = lo;
        *(u32*)(dst + 4) = hi;
    }
    // --- WTc: thread = channel; 8 slots of this block; fp8(w*16) packed 8B, kl-XOR swizzle ---
    {
        const int ch = t;
        const int chunk = m0 >> 6, kl0 = m0 & 63;
        u32 lo = 0, hi = 0;
#pragma unroll
        for (int i = 0; i < 8; ++i) {
            u32 bb = f2e4m3(W[(m0 + i) * 256 + ch] * 16.f);
            if (i < 4) lo |= bb << (i * 8); else hi |= bb << ((i - 4) * 8);
        }
        u8* dst = WTc + chunk * 16384 + ch * 64 + (kl0 ^ ((ch & 7) << 3));
        *(u32*)dst = lo;
        *(u32*)(dst + 4) = hi;
    }
    if (blk == 0 && t == 0) {
        loss[0] = 0.0f;
        loss[1] = -2000.0f / (2000.0f * 1999.0f);
    }
}

// ---------------- main fused kernel: 32 rows/block, 1024 blocks ----------------
__global__ __launch_bounds__(512, 1) void main_kernel(
        const float* __restrict__ inp, const float* __restrict__ posb,
        const u8* __restrict__ Wc, const u8* __restrict__ WTc,
        const float* __restrict__ sqv, float* __restrict__ out,
        float* __restrict__ loss) {
    __shared__ __align__(16) u8 pool[POOLSZ];
    __shared__ float sPM[4][32];
    __shared__ int   sPI[4][32];
    __shared__ float sPZ[4][32];
    __shared__ float sPD[4][32];
    __shared__ float sSS[8][32];
    __shared__ float sMax[32];
    __shared__ float sThr[32];
    __shared__ float sInv[32];

    const int t = threadIdx.x;
    const int w = t >> 6, lane = t & 63;
    const int ar = lane & 15, ag = lane >> 4;
    const int blk = blockIdx.x, b = blk >> 5, hw0 = (blk & 31) << 5;
    const int prot = ((blk >> 3) & 15) * 2;      // even chunk-rotation
    const int q = w & 3, rt = w >> 2;
    const int row_a = rt * 16 + ar;

    // ---- G1 prologue: logical sub-chunks 0..3 -> ring slots 0..3 (6-slot ring at pool[0,96K)) ----
#pragma unroll
    for (int cl = 0; cl < 4; ++cl) {
        const int pc = (cl + prot) & 31;
        const u8* src = Wc + pc * 16384 + w * 2048 + lane * 16;
        u8* dst = pool + (cl % 6) * 16384 + w * 2048;
        gl_lds16(src, dst);
        gl_lds16(src + 1024, dst + 1024);
    }

    // ---- stage xr as fp8 (x*4) at XRBASE; per-row sum(x^2) ----
    {
        const int hw = t & 31, cg = t >> 5;      // cg 0..15, 16 channels each
        const float* ip = inp + (size_t)b * 262144 + hw0 + hw;
        const float* pp = posb + hw0 + hw;
        float ss = 0.f;
        u8* xrow = pool + XRBASE + hw * XRS + cg * 16;
#pragma unroll
        for (int j = 0; j < 8; ++j) {
            const int ch = cg * 16 + 2 * j;
            float v0 = ip[ch * 1024] + pp[ch * 1024];
            float v1 = ip[(ch + 1) * 1024] + pp[(ch + 1) * 1024];
            ss += v0 * v0 + v1 * v1;
            u16 pk2 = (u16)(f2e4m3(v0 * 4.f) | (f2e4m3(v1 * 4.f) << 8));
            *(u16*)(xrow + 2 * j) = pk2;
        }
        ss += __shfl_xor(ss, 32);
        if (lane < 32) sSS[w][lane] = ss;
    }
    lds_bar();

    // ---- xr B-fragments: row_a, full K=256 (8 x 8B) ----
    s64 xB[8];
#pragma unroll
    for (int kk = 0; kk < 8; ++kk)
        xB[kk] = *(const s64*)(pool + XRBASE + row_a * XRS + kk * 32 + ag * 8);
    asm volatile("s_waitcnt lgkmcnt(0)" ::: "memory");
    __builtin_amdgcn_sched_barrier(0);

    // ---- GEMM1 (fp8): acc[c][e] = 64*logit[row_a][slot = pc*64 + q*16 + ag*4 + e] ----
    // 6-slot ring, 2 sub-chunks/iter, stage 2 iters ahead, counted vmcnt(4)
    f32x4 acc[32];
    const int c31 = (31 - prot) & 31;            // logical index of physical sub-chunk 31
    {
        const int rowoff = (q * 16 + ar) * 16;
#pragma unroll
        for (int i = 0; i < 16; ++i) {
            if (i <= 14) asm volatile("s_waitcnt vmcnt(4)" ::: "memory");
            else         asm volatile("s_waitcnt vmcnt(0)" ::: "memory");
            pipe_bar();
            if (i <= 13) {
#pragma unroll
                for (int u = 0; u < 2; ++u) {
                    const int cl = 2 * i + 4 + u;
                    const int pc = (cl + prot) & 31;
                    const u8* src = Wc + pc * 16384 + w * 2048 + lane * 16;
                    u8* dst = pool + (cl % 6) * 16384 + w * 2048;
                    gl_lds16(src, dst);
                    gl_lds16(src + 1024, dst + 1024);
                }
            }
#pragma unroll
            for (int u = 0; u < 2; ++u) {
                const int cl = 2 * i + u;
                const u8* base = pool + (cl % 6) * 16384 + rowoff;
                f32x4 a = {0.f, 0.f, 0.f, 0.f};
#pragma unroll
                for (int kp = 0; kp < 4; ++kp) {
                    s64x2 wA = *(const s64x2*)(base + (kp * 4 + ag) * 1024);
                    a = __builtin_amdgcn_mfma_f32_16x16x32_fp8_fp8(wA[0], xB[2 * kp], a, 0, 0, 0);
                    a = __builtin_amdgcn_mfma_f32_16x16x32_fp8_fp8(wA[1], xB[2 * kp + 1], a, 0, 0, 0);
                }
                if (cl == c31 && q != 0) { a[0] = -3e38f; a[1] = -3e38f; a[2] = -3e38f; a[3] = -3e38f; }
                acc[cl] = a;
            }
        }
    }

    // ---- per-thread max + argmax (one row per thread) ----
    {
        float bm = -3e38f; int bi = 0x7fffffff;
#pragma unroll
        for (int c = 0; c < 32; ++c) {
            const int cb = (((c + prot) & 31) << 6) + q * 16 + ag * 4;
#pragma unroll
            for (int e = 0; e < 4; ++e) {
                float f = acc[c][e];
                int id = cb + e;
                if (f > bm || (f == bm && id < bi)) { bm = f; bi = id; }
            }
        }
#pragma unroll
        for (int d = 16; d < 64; d <<= 1) {
            float om = __shfl_xor(bm, d);
            int   oi = __shfl_xor(bi, d);
            if (om > bm || (om == bm && oi < bi)) { bm = om; bi = oi; }
        }
        if (lane < 16) { sPM[q][rt * 16 + lane] = bm; sPI[q][rt * 16 + lane] = bi; }
    }

    // ---- G2 prologue: logical chunks 0,1 -> G2 ring slots 0,1 (G1 done reading) ----
#pragma unroll
    for (int u = 0; u < 2; ++u) {
        const int pc = (u + prot) & 31;
        const u8* src = WTc + pc * 16384 + w * 2048 + lane * 16;
        u8* dst = pool + RING2 + u * 16384 + w * 2048;
        gl_lds16(src, dst);
        gl_lds16(src + 1024, dst + 1024);
    }
    lds_bar();

    // ---- combine max/argmax + compact loss (logit = acc/64) ----
    if (t < 32) {
        float mx = sPM[0][t]; int bid = sPI[0][t];
#pragma unroll
        for (int qq = 1; qq < 4; ++qq) {
            float m2 = sPM[qq][t]; int i2 = sPI[qq][t];
            if (m2 > mx || (m2 == mx && i2 < bid)) { mx = m2; bid = i2; }
        }
        sMax[t] = mx;
        float ssq = 0.f;
#pragma unroll
        for (int ww = 0; ww < 8; ++ww) ssq += sSS[ww][t];
        float term = ssq - 2.f * (mx * 0.015625f) + sqv[bid];
#pragma unroll
        for (int d = 1; d < 32; d <<= 1) term += __shfl_xor(term, d);
        if (t == 0) atomicAdd(loss, term * (1.0f / 8388608.0f));
    }
    lds_bar();

    // ---- exp (in-place, scale 1/64) + Z ----
    {
        const float mxv = sMax[row_a];
        float z = 0.f;
#pragma unroll
        for (int c = 0; c < 32; ++c)
#pragma unroll
            for (int e = 0; e < 4; ++e) {
                float a_ = __expf((acc[c][e] - mxv) * 0.015625f);
                acc[c][e] = a_;
                z += a_;
            }
        z += __shfl_xor(z, 16); z += __shfl_xor(z, 32);
        if (lane < 16) sPZ[q][rt * 16 + lane] = z;
    }
    lds_bar();
    if (t < 32) sThr[t] = 0.0025f * (sPZ[0][t] + sPZ[1][t] + sPZ[2][t] + sPZ[3][t]);
    lds_bar();

    // ---- shrink mask + denom + packed fp8 a-write (u32/chunk, paired-k layout) ----
    {
        const float thrv = sThr[row_a];
        // new within-chunk offset for the 4 slots starting at sb = q*16 + ag*4
        const int newoff = (((q * 2 + (ag >> 1)) & 3) << 4) | ((q >> 1) << 3) | ((ag & 1) << 2);
        const int rowbase = row_a * SLSTR + newoff;
        float den = 0.f;
#pragma unroll
        for (int c = 0; c < 32; ++c) {
            const int off = rowbase + (((c + prot) & 31) << 6);
            u32 pk = 0;
#pragma unroll
            for (int e = 0; e < 4; ++e) {
                float a_ = acc[c][e];
                if (a_ > thrv) { den += a_; pk |= f2e4m3_fast(a_ * 64.f) << (e * 8); }
            }
            *(u32*)(pool + off) = pk;
        }
        den += __shfl_xor(den, 16); den += __shfl_xor(den, 32);
        if (lane < 16) sPD[q][rt * 16 + lane] = den;
    }
    lds_bar();
    if (t < 32) {
        float dd = sPD[0][t] + sPD[1][t] + sPD[2][t] + sPD[3][t];
        sInv[t] = dd > 0.f ? 1.0f / (1024.0f * dd) : 0.0f;
    }
    lds_bar();

    // ---- GEMM2: out = a_fp8 @ WT_fp8, 2 chunks/barrier; A-reads are b128 (paired-k) ----
    const int ch0 = (w * 2) * 16 + ar;
    const int ch1 = ch0 + 16;
    int bo[2][2];
#pragma unroll
    for (int kk = 0; kk < 2; ++kk) {
        bo[0][kk] = (ch0 * 64 + kk * 32 + ag * 8) ^ ((ch0 & 7) << 3);
        bo[1][kk] = (ch1 * 64 + kk * 32 + ag * 8) ^ ((ch1 & 7) << 3);
    }
    const u8* sLr0 = pool + ar * SLSTR + ag * 16;
    const u8* sLr1 = pool + (16 + ar) * SLSTR + ag * 16;
    f32x4 o00 = {0.f,0.f,0.f,0.f}, o01 = {0.f,0.f,0.f,0.f};
    f32x4 o10 = {0.f,0.f,0.f,0.f}, o11 = {0.f,0.f,0.f,0.f};
#pragma unroll
    for (int i = 0; i < 16; ++i) {
        asm volatile("s_waitcnt vmcnt(0)" ::: "memory");
        pipe_bar();
        if (i < 15) {
#pragma unroll
            for (int u = 0; u < 2; ++u) {
                const int cl = 2 * i + 2 + u;
                const int pc = (cl + prot) & 31;
                const u8* src = WTc + pc * 16384 + w * 2048 + lane * 16;
                u8* dst = pool + RING2 + (cl & 3) * 16384 + w * 2048;
                gl_lds16(src, dst);
                gl_lds16(src + 1024, dst + 1024);
            }
        }
#pragma unroll
        for (int u = 0; u < 2; ++u) {
            const int cl = 2 * i + u;
            const u8* base = pool + RING2 + (cl & 3) * 16384;
            const int cc64 = ((cl + prot) & 31) << 6;
            s64x2 A0 = *(const s64x2*)(sLr0 + cc64);
            s64x2 A1 = *(const s64x2*)(sLr1 + cc64);
            s64 B00 = *(const s64*)(base + bo[0][0]);
            s64 B01 = *(const s64*)(base + bo[0][1]);
            s64 B10 = *(const s64*)(base + bo[1][0]);
            s64 B11 = *(const s64*)(base + bo[1][1]);
            o00 = __builtin_amdgcn_mfma_f32_16x16x32_fp8_fp8(A0[0], B00, o00, 0, 0, 0);
            o00 = __builtin_amdgcn_mfma_f32_16x16x32_fp8_fp8(A0[1], B01, o00, 0, 0, 0);
            o01 = __builtin_amdgcn_mfma_f32_16x16x32_fp8_fp8(A1[0], B00, o01, 0, 0, 0);
            o01 = __builtin_amdgcn_mfma_f32_16x16x32_fp8_fp8(A1[1], B01, o01, 0, 0, 0);
            o10 = __builtin_amdgcn_mfma_f32_16x16x32_fp8_fp8(A0[0], B10, o10, 0, 0, 0);
            o10 = __builtin_amdgcn_mfma_f32_16x16x32_fp8_fp8(A0[1], B11, o10, 0, 0, 0);
            o11 = __builtin_amdgcn_mfma_f32_16x16x32_fp8_fp8(A1[0], B10, o11, 0, 0, 0);
            o11 = __builtin_amdgcn_mfma_f32_16x16x32_fp8_fp8(A1[1], B11, o11, 0, 0, 0);
        }
    }
    lds_bar();   // all a/ring reads done; reuse pool as f32 out-stage

    {
        float* sO = (float*)pool;
#pragma unroll
        for (int i = 0; i < 4; ++i) {
            int r0 = ag * 4 + i, r1 = 16 + ag * 4 + i;
            sO[r0 * OSTR + ch0] = o00[i] * sInv[r0];
            sO[r1 * OSTR + ch0] = o01[i] * sInv[r1];
            sO[r0 * OSTR + ch1] = o10[i] * sInv[r0];
            sO[r1 * OSTR + ch1] = o11[i] * sInv[r1];
        }
    }
    lds_bar();
    {
        const float* sO = (const float*)pool;
        const int hw = t & 31, cq = t >> 5;
        float* op = out + (size_t)b * 262144 + hw0 + hw;
#pragma unroll
        for (int i = 0; i < 16; ++i) {
            int ch = cq + (i << 4);
            op[ch * 1024] = sO[hw * OSTR + ch];
        }
    }
}

// ---------------- distance loss from fp8 Wc (paired-k layout): acc/128 covers 2<wi,wj> ----------
__global__ __launch_bounds__(256) void dist_kernel(const u8* __restrict__ Wc,
                                                   const float* __restrict__ sqv,
                                                   float* __restrict__ dl) {
    __shared__ float red[4];
    int t = threadIdx.x, w = t >> 6, lane = t & 63;
    int ar = lane & 15, ag = lane >> 4;
    const int i0 = blockIdx.x << 4;
    const int ci = i0 >> 6, si0 = i0 & 63;
    s64x2 af2[4];
#pragma unroll
    for (int kp = 0; kp < 4; ++kp)
        af2[kp] = *(const s64x2*)(Wc + ci * 16384 + (size_t)((kp * 4 + ag) * 64 + si0 + ar) * 16);
    float sqi[4];
#pragma unroll
    for (int e = 0; e < 4; ++e) sqi[e] = sqv[i0 + ag * 4 + e];
    float sum = 0.f;
    for (int jt = w; jt < 125; jt += 4) {
        const int j0 = jt << 4;
        const int cj = j0 >> 6, sj0 = j0 & 63;
        f32x4 acc = {0.f, 0.f, 0.f, 0.f};
#pragma unroll
        for (int kp = 0; kp < 4; ++kp) {
            s64x2 bf = *(const s64x2*)(Wc + cj * 16384 + (size_t)((kp * 4 + ag) * 64 + sj0 + ar) * 16);
            acc = __builtin_amdgcn_mfma_f32_16x16x32_fp8_fp8(af2[kp][0], bf[0], acc, 0, 0, 0);
            acc = __builtin_amdgcn_mfma_f32_16x16x32_fp8_fp8(af2[kp][1], bf[1], acc, 0, 0, 0);
        }
        float sqj = sqv[j0 + ar];
#pragma unroll
        for (int e = 0; e < 4; ++e) {
            float dist = 1.0f - (sqi[e] + sqj - acc[e] * 0.0078125f);
            sum += dist > 0.f ? dist : 0.f;
        }
    }
#pragma unroll
    for (int d = 1; d < 64; d <<= 1) sum += __shfl_xor(sum, d);
    if (lane == 0) red[w] = sum;
    __syncthreads();
    if (t == 0) {
        float s = red[0] + red[1] + red[2] + red[3];
        atomicAdd(dl, s * (1.0f / (2000.0f * 1999.0f)));
    }
}

extern "C" void kernel_launch(void* const* d_in, const int* in_sizes, int n_in,
                              void* d_out, int out_size, void* d_ws, size_t ws_size,
                              hipStream_t stream) {
    (void)in_sizes; (void)n_in; (void)out_size; (void)ws_size;
    const float* inp  = (const float*)d_in[0];
    const float* W    = (const float*)d_in[2];
    const float* posb = (const float*)d_in[3];
    float* out = (float*)d_out;

    u8* WTc = (u8*)d_ws;                                     // 32*16384 = 524,288 B
    u8* Wc  = (u8*)d_ws + 524288;                            // 32*16384 = 524,288 B
    float* sqv = (float*)((u8*)d_ws + 1048576);              // 2000*4   =   8,000 B

    hipLaunchKernelGGL(prep_kernel, dim3(250), dim3(256), 0, stream, W, WTc, Wc, sqv, out + OUTN);
    hipLaunchKernelGGL(main_kernel, dim3(1024), dim3(512), 0, stream, inp, posb, Wc, WTc, sqv, out, out + OUTN);
    hipLaunchKernelGGL(dist_kernel, dim3(125), dim3(256), 0, stream, Wc, sqv, out + OUTN + 1);
}

// Round 10
// 169.188 us; speedup vs baseline: 4.4382x; 1.0300x over previous
//
#include <hip/hip_runtime.h>
#include <hip/hip_bf16.h>

typedef unsigned char u8;
typedef unsigned short u16;
typedef unsigned int u32;
typedef long long s64;
typedef float f32x4 __attribute__((ext_vector_type(4)));
typedef long long s64x2 __attribute__((ext_vector_type(2)));

#define MEM    2000
#define FEA    256
#define SLSTR  2064      // fp8 a row stride (bytes), 16B-aligned
#define OSTR   265       // out-stage row stride (f32)
#define XRS    264       // xr fp8 row stride (bytes)
#define POOLSZ 66048     // a-matrix 32*SLSTR; xr + out-stage overlap inside
#define OUTN   8388608   // 32*256*32*32

// exact f32 -> e4m3fn (RNE) incl subnormals
__device__ __forceinline__ u32 f2e4m3(float x) {
    float ax = fabsf(x);
    u32 s = (__builtin_bit_cast(u32, x) >> 24) & 0x80u;
    if (ax >= 448.f) return s | 0x7e;
    if (ax < 0.015625f) {
        int q = (int)rintf(ax * 512.f);
        return s | (u32)q;
    }
    int e = (int)(__builtin_bit_cast(u32, ax) >> 23) - 127;
    float scale = __builtin_bit_cast(float, (u32)((127 - e + 3) << 23));
    int q = (int)rintf(ax * scale);
    int E = e + 7;
    if (q == 16) { q = 8; E += 1; if (E > 15) return s | 0x7e; }
    return s | (u32)(E << 3) | (u32)(q & 7);
}
// fast f32 -> e4m3fn for v in {0} U [0.15, 64]
__device__ __forceinline__ u32 f2e4m3_fast(float v) {
    u32 u = __builtin_bit_cast(u32, v);
    u += 0x0007FFFFu + ((u >> 20) & 1u);
    int bb = (int)(u >> 20) - 0x3C0;
    return bb < 0 ? 0u : (u32)bb;
}

// ---------------- prep ----------------
// Wc (G1 A-operand, paired-k): byte[c*16384 + ((kp*4+ag)*64 + s)*16 + klo*8 + j]
//   = fp8( W[c*64+s][(2*kp+klo)*32 + ag*8 + j] * 16 )
// WTc (G2 B-operand, packed-pair): byte[c*16384 + ch*64 + agp*16 + klo*8 + j]
//   = fp8( W[c*64 + klo*32 + agp*8 + j][ch] * 16 )
__global__ __launch_bounds__(256) void prep_kernel(const float* __restrict__ W,
                                                   u8* __restrict__ WTc,
                                                   u8* __restrict__ Wc,
                                                   float* __restrict__ sqv,
                                                   float* __restrict__ loss) {
    const int blk = blockIdx.x, t = threadIdx.x;
    const int m0 = blk * 8;
    // --- Wc + sqv ---
    {
        const int sl = t >> 5, cl = t & 31;
        const int slot = m0 + sl;
        const int ch0 = cl * 8;
        const float* wr = W + slot * 256 + ch0;
        f32x4 v0 = *(const f32x4*)wr;
        f32x4 v1 = *(const f32x4*)(wr + 4);
        float ss = v0[0]*v0[0] + v0[1]*v0[1] + v0[2]*v0[2] + v0[3]*v0[3]
                 + v1[0]*v1[0] + v1[1]*v1[1] + v1[2]*v1[2] + v1[3]*v1[3];
        ss += __shfl_xor(ss, 1); ss += __shfl_xor(ss, 2); ss += __shfl_xor(ss, 4);
        ss += __shfl_xor(ss, 8); ss += __shfl_xor(ss, 16);
        if (cl == 0) sqv[slot] = ss;
        const int c = slot >> 6, s = slot & 63;
        const int kk = cl >> 2, agp = cl & 3;
        const int kp = kk >> 1, klo = kk & 1;
        u32 lo = 0, hi = 0;
#pragma unroll
        for (int i = 0; i < 4; ++i) {
            lo |= f2e4m3(v0[i] * 16.f) << (i * 8);
            hi |= f2e4m3(v1[i] * 16.f) << (i * 8);
        }
        u8* dst = Wc + c * 16384 + (size_t)((kp * 4 + agp) * 64 + s) * 16 + klo * 8;
        *(u32*)dst = lo;
        *(u32*)(dst + 4) = hi;
    }
    // --- WTc packed-pair, plain (no swizzle) ---
    {
        const int ch = t;
        const int chunk = m0 >> 6;
        const int kl0 = m0 & 63;
        const int klo = kl0 >> 5, agp = (kl0 & 31) >> 3;
        u32 lo = 0, hi = 0;
#pragma unroll
        for (int i = 0; i < 8; ++i) {
            u32 bb = f2e4m3(W[(m0 + i) * 256 + ch] * 16.f);
            if (i < 4) lo |= bb << (i * 8); else hi |= bb << ((i - 4) * 8);
        }
        u8* dst = WTc + chunk * 16384 + ch * 64 + agp * 16 + klo * 8;
        *(u32*)dst = lo;
        *(u32*)(dst + 4) = hi;
    }
    if (blk == 0 && t == 0) {
        loss[0] = 0.0f;
        loss[1] = -2000.0f / (2000.0f * 1999.0f);
    }
}

// ---------------- main fused kernel: 32 rows/block, 1024 blocks, barrier-light ----------------
__global__ __launch_bounds__(512, 1) void main_kernel(
        const float* __restrict__ inp, const float* __restrict__ posb,
        const u8* __restrict__ Wc, const u8* __restrict__ WTc,
        const float* __restrict__ sqv, float* __restrict__ out,
        float* __restrict__ loss) {
    __shared__ __align__(16) u8 pool[POOLSZ];
    __shared__ float sPM[4][32];
    __shared__ int   sPI[4][32];
    __shared__ float sPZ[4][32];
    __shared__ float sPD[4][32];
    __shared__ float sSS[8][32];
    __shared__ float sMax[32];
    __shared__ float sThr[32];
    __shared__ float sInv[32];

    const int t = threadIdx.x;
    const int w = t >> 6, lane = t & 63;
    const int ar = lane & 15, ag = lane >> 4;
    const int blk = blockIdx.x, b = blk >> 5, hw0 = (blk & 31) << 5;
    const int prot = ((blk >> 3) & 15) * 2;      // chunk rotation for L2 spread
    const int q = w & 3, rt = w >> 2;
    const int row_a = rt * 16 + ar;

    // ---- phase A: stage xr as fp8 (x*4) at pool[0, 8448); per-row sum(x^2) ----
    {
        const int hw = t & 31, cg = t >> 5;
        const float* ip = inp + (size_t)b * 262144 + hw0 + hw;
        const float* pp = posb + hw0 + hw;
        float ss = 0.f;
        u8* xrow = pool + hw * XRS + cg * 16;
#pragma unroll
        for (int j = 0; j < 8; ++j) {
            const int ch = cg * 16 + 2 * j;
            float v0 = ip[ch * 1024] + pp[ch * 1024];
            float v1 = ip[(ch + 1) * 1024] + pp[(ch + 1) * 1024];
            ss += v0 * v0 + v1 * v1;
            u16 pk2 = (u16)(f2e4m3(v0 * 4.f) | (f2e4m3(v1 * 4.f) << 8));
            *(u16*)(xrow + 2 * j) = pk2;
        }
        ss += __shfl_xor(ss, 32);
        if (lane < 32) sSS[w][lane] = ss;
    }
    __syncthreads();

    // ---- xr B-fragments: row_a, full K=256 (8 x 8B) ----
    s64 xB[8];
#pragma unroll
    for (int kk = 0; kk < 8; ++kk)
        xB[kk] = *(const s64*)(pool + row_a * XRS + kk * 32 + ag * 8);

    // ---- GEMM1 (fp8, direct global->reg): acc[c][e] = 64*logit[row_a][pc*64 + q*16 + ag*4 + e] ----
    f32x4 acc[32];
    const int c31 = (31 - prot) & 31;
    {
        const u8* wbase = Wc + ag * 1024 + (q * 16 + ar) * 16;
#pragma unroll
        for (int c = 0; c < 32; ++c) {
            const int pc = (c + prot) & 31;
            const u8* p = wbase + pc * 16384;
            s64x2 w0 = *(const s64x2*)(p);
            s64x2 w1 = *(const s64x2*)(p + 4096);
            s64x2 w2 = *(const s64x2*)(p + 8192);
            s64x2 w3 = *(const s64x2*)(p + 12288);
            f32x4 a = {0.f, 0.f, 0.f, 0.f};
            a = __builtin_amdgcn_mfma_f32_16x16x32_fp8_fp8(w0[0], xB[0], a, 0, 0, 0);
            a = __builtin_amdgcn_mfma_f32_16x16x32_fp8_fp8(w0[1], xB[1], a, 0, 0, 0);
            a = __builtin_amdgcn_mfma_f32_16x16x32_fp8_fp8(w1[0], xB[2], a, 0, 0, 0);
            a = __builtin_amdgcn_mfma_f32_16x16x32_fp8_fp8(w1[1], xB[3], a, 0, 0, 0);
            a = __builtin_amdgcn_mfma_f32_16x16x32_fp8_fp8(w2[0], xB[4], a, 0, 0, 0);
            a = __builtin_amdgcn_mfma_f32_16x16x32_fp8_fp8(w2[1], xB[5], a, 0, 0, 0);
            a = __builtin_amdgcn_mfma_f32_16x16x32_fp8_fp8(w3[0], xB[6], a, 0, 0, 0);
            a = __builtin_amdgcn_mfma_f32_16x16x32_fp8_fp8(w3[1], xB[7], a, 0, 0, 0);
            if (c == c31 && q != 0) { a[0] = -3e38f; a[1] = -3e38f; a[2] = -3e38f; a[3] = -3e38f; }
            acc[c] = a;
        }
    }

    // ---- per-thread max + argmax (one row per thread) ----
    {
        float bm = -3e38f; int bi = 0x7fffffff;
#pragma unroll
        for (int c = 0; c < 32; ++c) {
            const int cb = (((c + prot) & 31) << 6) + q * 16 + ag * 4;
#pragma unroll
            for (int e = 0; e < 4; ++e) {
                float f = acc[c][e];
                int id = cb + e;
                if (f > bm || (f == bm && id < bi)) { bm = f; bi = id; }
            }
        }
#pragma unroll
        for (int d = 16; d < 64; d <<= 1) {
            float om = __shfl_xor(bm, d);
            int   oi = __shfl_xor(bi, d);
            if (om > bm || (om == bm && oi < bi)) { bm = om; bi = oi; }
        }
        if (lane < 16) { sPM[q][rt * 16 + lane] = bm; sPI[q][rt * 16 + lane] = bi; }
    }
    __syncthreads();

    // ---- combine max/argmax + compact loss (logit = acc/64) ----
    if (t < 32) {
        float mx = sPM[0][t]; int bid = sPI[0][t];
#pragma unroll
        for (int qq = 1; qq < 4; ++qq) {
            float m2 = sPM[qq][t]; int i2 = sPI[qq][t];
            if (m2 > mx || (m2 == mx && i2 < bid)) { mx = m2; bid = i2; }
        }
        sMax[t] = mx;
        float ssq = 0.f;
#pragma unroll
        for (int ww = 0; ww < 8; ++ww) ssq += sSS[ww][t];
        float term = ssq - 2.f * (mx * 0.015625f) + sqv[bid];
#pragma unroll
        for (int d = 1; d < 32; d <<= 1) term += __shfl_xor(term, d);
        if (t == 0) atomicAdd(loss, term * (1.0f / 8388608.0f));
    }
    __syncthreads();

    // ---- exp (in-place, scale 1/64) + Z ----
    {
        const float mxv = sMax[row_a];
        float z = 0.f;
#pragma unroll
        for (int c = 0; c < 32; ++c)
#pragma unroll
            for (int e = 0; e < 4; ++e) {
                float a_ = __expf((acc[c][e] - mxv) * 0.015625f);
                acc[c][e] = a_;
                z += a_;
            }
        z += __shfl_xor(z, 16); z += __shfl_xor(z, 32);
        if (lane < 16) sPZ[q][rt * 16 + lane] = z;
    }
    __syncthreads();
    if (t < 32) sThr[t] = 0.0025f * (sPZ[0][t] + sPZ[1][t] + sPZ[2][t] + sPZ[3][t]);
    __syncthreads();

    // ---- shrink mask + denom + packed fp8 a-write (u32/chunk, paired-k layout) ----
    {
        const float thrv = sThr[row_a];
        const int newoff = (((q * 2 + (ag >> 1)) & 3) << 4) | ((q >> 1) << 3) | ((ag & 1) << 2);
        const int rowbase = row_a * SLSTR + newoff;
        float den = 0.f;
#pragma unroll
        for (int c = 0; c < 32; ++c) {
            const int off = rowbase + (((c + prot) & 31) << 6);
            u32 pk = 0;
#pragma unroll
            for (int e = 0; e < 4; ++e) {
                float a_ = acc[c][e];
                if (a_ > thrv) { den += a_; pk |= f2e4m3_fast(a_ * 64.f) << (e * 8); }
            }
            *(u32*)(pool + off) = pk;
        }
        den += __shfl_xor(den, 16); den += __shfl_xor(den, 32);
        if (lane < 16) sPD[q][rt * 16 + lane] = den;
    }
    __syncthreads();
    if (t < 32) {
        float dd = sPD[0][t] + sPD[1][t] + sPD[2][t] + sPD[3][t];
        sInv[t] = dd > 0.f ? 1.0f / (1024.0f * dd) : 0.0f;
    }
    __syncthreads();

    // ---- GEMM2: out = a_fp8 @ WT_fp8; A from LDS a-matrix, B direct global->reg ----
    const int ch0 = (w * 2) * 16 + ar;
    const int ch1 = ch0 + 16;
    const u8* sLr0 = pool + ar * SLSTR + ag * 16;
    const u8* sLr1 = pool + (16 + ar) * SLSTR + ag * 16;
    const u8* wt0 = WTc + ch0 * 64 + ag * 16;
    const u8* wt1 = WTc + ch1 * 64 + ag * 16;
    f32x4 o00 = {0.f,0.f,0.f,0.f}, o01 = {0.f,0.f,0.f,0.f};
    f32x4 o10 = {0.f,0.f,0.f,0.f}, o11 = {0.f,0.f,0.f,0.f};
#pragma unroll
    for (int c = 0; c < 32; ++c) {
        const int pc = (c + prot) & 31;
        const int cc64 = pc << 6;
        s64x2 B0 = *(const s64x2*)(wt0 + pc * 16384);
        s64x2 B1 = *(const s64x2*)(wt1 + pc * 16384);
        s64x2 A0 = *(const s64x2*)(sLr0 + cc64);
        s64x2 A1 = *(const s64x2*)(sLr1 + cc64);
        o00 = __builtin_amdgcn_mfma_f32_16x16x32_fp8_fp8(A0[0], B0[0], o00, 0, 0, 0);
        o00 = __builtin_amdgcn_mfma_f32_16x16x32_fp8_fp8(A0[1], B0[1], o00, 0, 0, 0);
        o01 = __builtin_amdgcn_mfma_f32_16x16x32_fp8_fp8(A1[0], B0[0], o01, 0, 0, 0);
        o01 = __builtin_amdgcn_mfma_f32_16x16x32_fp8_fp8(A1[1], B0[1], o01, 0, 0, 0);
        o10 = __builtin_amdgcn_mfma_f32_16x16x32_fp8_fp8(A0[0], B1[0], o10, 0, 0, 0);
        o10 = __builtin_amdgcn_mfma_f32_16x16x32_fp8_fp8(A0[1], B1[1], o10, 0, 0, 0);
        o11 = __builtin_amdgcn_mfma_f32_16x16x32_fp8_fp8(A1[0], B1[0], o11, 0, 0, 0);
        o11 = __builtin_amdgcn_mfma_f32_16x16x32_fp8_fp8(A1[1], B1[1], o11, 0, 0, 0);
    }
    __syncthreads();   // all a-reads done; reuse pool as f32 out-stage

    {
        float* sO = (float*)pool;
#pragma unroll
        for (int i = 0; i < 4; ++i) {
            int r0 = ag * 4 + i, r1 = 16 + ag * 4 + i;
            sO[r0 * OSTR + ch0] = o00[i] * sInv[r0];
            sO[r1 * OSTR + ch0] = o01[i] * sInv[r1];
            sO[r0 * OSTR + ch1] = o10[i] * sInv[r0];
            sO[r1 * OSTR + ch1] = o11[i] * sInv[r1];
        }
    }
    __syncthreads();
    {
        const float* sO = (const float*)pool;
        const int hw = t & 31, cq = t >> 5;
        float* op = out + (size_t)b * 262144 + hw0 + hw;
#pragma unroll
        for (int i = 0; i < 16; ++i) {
            int ch = cq + (i << 4);
            op[ch * 1024] = sO[hw * OSTR + ch];
        }
    }
}

// ---------------- distance loss from fp8 Wc (paired-k layout) ----------------
__global__ __launch_bounds__(256) void dist_kernel(const u8* __restrict__ Wc,
                                                   const float* __restrict__ sqv,
                                                   float* __restrict__ dl) {
    __shared__ float red[4];
    int t = threadIdx.x, w = t >> 6, lane = t & 63;
    int ar = lane & 15, ag = lane >> 4;
    const int i0 = blockIdx.x << 4;
    const int ci = i0 >> 6, si0 = i0 & 63;
    s64x2 af2[4];
#pragma unroll
    for (int kp = 0; kp < 4; ++kp)
        af2[kp] = *(const s64x2*)(Wc + ci * 16384 + (size_t)((kp * 4 + ag) * 64 + si0 + ar) * 16);
    float sqi[4];
#pragma unroll
    for (int e = 0; e < 4; ++e) sqi[e] = sqv[i0 + ag * 4 + e];
    float sum = 0.f;
    for (int jt = w; jt < 125; jt += 4) {
        const int j0 = jt << 4;
        const int cj = j0 >> 6, sj0 = j0 & 63;
        f32x4 acc = {0.f, 0.f, 0.f, 0.f};
#pragma unroll
        for (int kp = 0; kp < 4; ++kp) {
            s64x2 bf = *(const s64x2*)(Wc + cj * 16384 + (size_t)((kp * 4 + ag) * 64 + sj0 + ar) * 16);
            acc = __builtin_amdgcn_mfma_f32_16x16x32_fp8_fp8(af2[kp][0], bf[0], acc, 0, 0, 0);
            acc = __builtin_amdgcn_mfma_f32_16x16x32_fp8_fp8(af2[kp][1], bf[1], acc, 0, 0, 0);
        }
        float sqj = sqv[j0 + ar];
#pragma unroll
        for (int e = 0; e < 4; ++e) {
            float dist = 1.0f - (sqi[e] + sqj - acc[e] * 0.0078125f);
            sum += dist > 0.f ? dist : 0.f;
        }
    }
#pragma unroll
    for (int d = 1; d < 64; d <<= 1) sum += __shfl_xor(sum, d);
    if (lane == 0) red[w] = sum;
    __syncthreads();
    if (t == 0) {
        float s = red[0] + red[1] + red[2] + red[3];
        atomicAdd(dl, s * (1.0f / (2000.0f * 1999.0f)));
    }
}

extern "C" void kernel_launch(void* const* d_in, const int* in_sizes, int n_in,
                              void* d_out, int out_size, void* d_ws, size_t ws_size,
                              hipStream_t stream) {
    (void)in_sizes; (void)n_in; (void)out_size; (void)ws_size;
    const float* inp  = (const float*)d_in[0];
    const float* W    = (const float*)d_in[2];
    const float* posb = (const float*)d_in[3];
    float* out = (float*)d_out;

    u8* WTc = (u8*)d_ws;                                     // 32*16384 = 524,288 B
    u8* Wc  = (u8*)d_ws + 524288;                            // 32*16384 = 524,288 B
    float* sqv = (float*)((u8*)d_ws + 1048576);              // 2000*4   =   8,000 B

    hipLaunchKernelGGL(prep_kernel, dim3(250), dim3(256), 0, stream, W, WTc, Wc, sqv, out + OUTN);
    hipLaunchKernelGGL(main_kernel, dim3(1024), dim3(512), 0, stream, inp, posb, Wc, WTc, sqv, out, out + OUTN);
    hipLaunchKernelGGL(dist_kernel, dim3(125), dim3(256), 0, stream, Wc, sqv, out + OUTN + 1);
}